// Round 1
// baseline (1208.911 us; speedup 1.0000x reference)
//
#include <hip/hip_runtime.h>
#include <hip/hip_bf16.h>
#include <cstddef>

// Problem constants
// B=8, M=512, H=512, K=8 heads, D=64, L=1024, key len = M+L = 1536
// score[bh,m,l] = q[bh,m,:]·(k[bh,m+l,:] + pe_t[l,:]) * 0.125
// out[bh,m,:]  = sum_l softmax_l(score) * v[bh,m+l,:]

#define HDIM 512
#define MQ 512
#define NK 1536
#define LSPAN 1024

// ---------------------------------------------------------------------------
// pe transpose: [D=64, L=1024] -> [L=1024, D=64]
__global__ void transpose_pe(const float* __restrict__ pe, float* __restrict__ pe_t) {
  int idx = blockIdx.x * 256 + threadIdx.x;  // 65536 total
  int l = idx >> 6;
  int d = idx & 63;
  pe_t[idx] = pe[d * LSPAN + l];
}

// ---------------------------------------------------------------------------
// C[r,h] = sum_i A[r,i] * W[h,i]   (A:[R,512] row-major, W:[512,512] row-major)
// 64x64 block tile, 256 threads, 4x4 per thread, k-chunk 32, LDS k-major.
__global__ __launch_bounds__(256) void gemm_nt(const float* __restrict__ A,
                                               const float* __restrict__ W,
                                               float* __restrict__ C) {
  __shared__ float As[32][68];  // [kk][row], pad 68 keeps 16B alignment, <=4-way store conflict
  __shared__ float Ws[32][68];  // [kk][col]
  const int tid = threadIdx.x;
  const int row0 = blockIdx.x * 64;
  const int col0 = blockIdx.y * 64;
  const int tx = tid & 15;
  const int ty = tid >> 4;
  float acc[4][4] = {};

  for (int k0 = 0; k0 < HDIM; k0 += 32) {
    __syncthreads();
#pragma unroll
    for (int i = 0; i < 2; ++i) {
      int idx = tid + i * 256;          // 512 float4 loads per operand tile
      int r = idx >> 3;                 // 0..63
      int c4 = (idx & 7) * 4;           // 0,4,...,28
      float4 av = *(const float4*)(A + (size_t)(row0 + r) * HDIM + k0 + c4);
      As[c4 + 0][r] = av.x;
      As[c4 + 1][r] = av.y;
      As[c4 + 2][r] = av.z;
      As[c4 + 3][r] = av.w;
      float4 wv = *(const float4*)(W + (size_t)(col0 + r) * HDIM + k0 + c4);
      Ws[c4 + 0][r] = wv.x;
      Ws[c4 + 1][r] = wv.y;
      Ws[c4 + 2][r] = wv.z;
      Ws[c4 + 3][r] = wv.w;
    }
    __syncthreads();
#pragma unroll
    for (int kk = 0; kk < 32; ++kk) {
      float4 a4 = *(const float4*)&As[kk][ty * 4];
      float4 b4 = *(const float4*)&Ws[kk][tx * 4];
      float av[4] = {a4.x, a4.y, a4.z, a4.w};
      float bv[4] = {b4.x, b4.y, b4.z, b4.w};
#pragma unroll
      for (int i = 0; i < 4; ++i)
#pragma unroll
        for (int j = 0; j < 4; ++j)
          acc[i][j] += av[i] * bv[j];
    }
  }
#pragma unroll
  for (int i = 0; i < 4; ++i) {
    float4 o = make_float4(acc[i][0], acc[i][1], acc[i][2], acc[i][3]);
    *(float4*)(C + (size_t)(row0 + ty * 4 + i) * HDIM + col0 + tx * 4) = o;
  }
}

// ---------------------------------------------------------------------------
// Fused banded attention, one block per (m, bh). 256 threads = 4 waves.
// q/k/v kept in [B, T, H] layout; head slice at h = kh*64.
__global__ __launch_bounds__(256) void attn_kernel(const float* __restrict__ q,
                                                   const float* __restrict__ k,
                                                   const float* __restrict__ v,
                                                   const float* __restrict__ pe_t,
                                                   float* __restrict__ ao) {
  const int m = blockIdx.x;
  const int bh = blockIdx.y;
  const int b = bh >> 3;
  const int kh = bh & 7;
  const int tid = threadIdx.x;
  const int lane = tid & 63;
  const int w = tid >> 6;

  __shared__ float p[LSPAN];
  __shared__ float red[16];
  __shared__ float accs[4][64];

  const float* qp = q + ((size_t)b * MQ + m) * HDIM + kh * 64;

  // ---- phase 1: scores. 16 lanes per l (4 d each), 16 l per block-iter.
  const int sub = lane & 15;     // d-group
  const int lg = lane >> 4;      // l-subindex within wave
  float4 qv = *(const float4*)(qp + sub * 4);
  const float* kbase = k + ((size_t)b * NK + m) * HDIM + kh * 64 + sub * 4;
#pragma unroll 4
  for (int it = 0; it < 64; ++it) {
    int l = it * 16 + w * 4 + lg;
    float4 kv = *(const float4*)(kbase + (size_t)l * HDIM);
    float4 pv = *(const float4*)(pe_t + l * 64 + sub * 4);
    float val = qv.x * (kv.x + pv.x) + qv.y * (kv.y + pv.y) +
                qv.z * (kv.z + pv.z) + qv.w * (kv.w + pv.w);
    val += __shfl_xor(val, 1, 64);
    val += __shfl_xor(val, 2, 64);
    val += __shfl_xor(val, 4, 64);
    val += __shfl_xor(val, 8, 64);
    if (sub == 0) p[l] = val * 0.125f;  // 1/sqrt(64)
  }
  __syncthreads();

  // ---- phase 2: softmax over p[0..1023]
  float vals[4];
  float lm = -1e30f;
#pragma unroll
  for (int i = 0; i < 4; ++i) {
    vals[i] = p[tid + i * 256];
    lm = fmaxf(lm, vals[i]);
  }
#pragma unroll
  for (int off = 32; off; off >>= 1) lm = fmaxf(lm, __shfl_xor(lm, off, 64));
  if (lane == 0) red[w] = lm;
  __syncthreads();
  float mx = fmaxf(fmaxf(red[0], red[1]), fmaxf(red[2], red[3]));
  float ls = 0.f;
#pragma unroll
  for (int i = 0; i < 4; ++i) {
    vals[i] = __expf(vals[i] - mx);
    ls += vals[i];
    p[tid + i * 256] = vals[i];
  }
#pragma unroll
  for (int off = 32; off; off >>= 1) ls += __shfl_xor(ls, off, 64);
  if (lane == 0) red[8 + w] = ls;
  __syncthreads();
  float inv = 1.0f / (red[8] + red[9] + red[10] + red[11]);

  // ---- phase 3: out[d] = inv * sum_l p[l] * v[m+l, d]
  const float* vbase = v + ((size_t)b * NK + m) * HDIM + kh * 64 + lane;
  float acc = 0.f;
#pragma unroll 4
  for (int j = 0; j < 256; ++j) {
    int l = j * 4 + w;
    acc += p[l] * vbase[(size_t)l * HDIM];
  }
  accs[w][lane] = acc;
  __syncthreads();
  if (tid < 64) {
    float o = (accs[0][tid] + accs[1][tid] + accs[2][tid] + accs[3][tid]) * inv;
    ao[((size_t)b * MQ + m) * HDIM + kh * 64 + tid] = o;
  }
}

// ---------------------------------------------------------------------------
extern "C" void kernel_launch(void* const* d_in, const int* in_sizes, int n_in,
                              void* d_out, int out_size, void* d_ws, size_t ws_size,
                              hipStream_t stream) {
  const float* query  = (const float*)d_in[0];
  const float* key    = (const float*)d_in[1];
  const float* value  = (const float*)d_in[2];
  const float* key_pe = (const float*)d_in[3];
  const float* Wq     = (const float*)d_in[4];
  const float* Wk     = (const float*)d_in[5];
  const float* Wv     = (const float*)d_in[6];
  const float* Wo     = (const float*)d_in[7];
  float* out = (float*)d_out;

  float* ws  = (float*)d_ws;
  float* qws = ws;                     // [8,512,512]   = 2,097,152
  float* kws = qws + 2097152;          // [8,1536,512]  = 6,291,456
  float* vws = kws + 6291456;          // [8,1536,512]  = 6,291,456
  float* pet = vws + 6291456;          // [1024,64]     = 65,536
  float* aow = pet + 65536;            // [8,512,512]   = 2,097,152
  // total = 16,842,752 floats = 64.25 MB

  hipLaunchKernelGGL(transpose_pe, dim3(256), dim3(256), 0, stream, key_pe, pet);
  hipLaunchKernelGGL(gemm_nt, dim3(64, 8),  dim3(256), 0, stream, query, Wq, qws);
  hipLaunchKernelGGL(gemm_nt, dim3(192, 8), dim3(256), 0, stream, key,   Wk, kws);
  hipLaunchKernelGGL(gemm_nt, dim3(192, 8), dim3(256), 0, stream, value, Wv, vws);
  hipLaunchKernelGGL(attn_kernel, dim3(512, 64), dim3(256), 0, stream,
                     qws, kws, vws, pet, aow);
  hipLaunchKernelGGL(gemm_nt, dim3(64, 8), dim3(256), 0, stream, aow, Wo, out);
}

// Round 2
// 433.690 us; speedup vs baseline: 2.7875x; 2.7875x over previous
//
#include <hip/hip_runtime.h>
#include <hip/hip_bf16.h>
#include <cstddef>
#include <math.h>

// B=8, M=512, H=512, K=8 heads, D=64, L=1024, key len = 1536
// score[bh,m,l] = q[bh,m,:]·k[bh,m+l,:]*0.125 + q[bh,m,:]·pe_t[l,:]*0.125
// out[bh,m,:]  = sum_l softmax_l(score) * v[bh,m+l,:]

#define HDIM 512
#define MQ 512
#define NK 1536
#define LSPAN 1024

typedef __bf16 bf16_t;
typedef bf16_t bf16x8 __attribute__((ext_vector_type(8)));
typedef bf16_t bf16x4 __attribute__((ext_vector_type(4)));
typedef float f32x4 __attribute__((ext_vector_type(4)));

#define MFMA16(a, b, c) __builtin_amdgcn_mfma_f32_16x16x32_bf16((a), (b), (c), 0, 0, 0)

// ---------------------------------------------------------------------------
// pe transpose + bf16 cast: [64,1024] f32 -> [1024,64] bf16
__global__ void transpose_pe(const float* __restrict__ pe, bf16_t* __restrict__ pet) {
  int idx = blockIdx.x * 256 + threadIdx.x;  // 65536 total
  int d = idx >> 10;
  int l = idx & 1023;
  pet[l * 64 + d] = (bf16_t)pe[idx];  // read coalesced, write scattered (tiny)
}

// ---------------------------------------------------------------------------
// fp32 NT GEMM (unchanged from round 0): C[r,h] = sum_i A[r,i]*W[h,i]
__global__ __launch_bounds__(256) void gemm_nt(const float* __restrict__ A,
                                               const float* __restrict__ W,
                                               float* __restrict__ C) {
  __shared__ float As[32][68];
  __shared__ float Ws[32][68];
  const int tid = threadIdx.x;
  const int row0 = blockIdx.x * 64;
  const int col0 = blockIdx.y * 64;
  const int tx = tid & 15;
  const int ty = tid >> 4;
  float acc[4][4] = {};

  for (int k0 = 0; k0 < HDIM; k0 += 32) {
    __syncthreads();
#pragma unroll
    for (int i = 0; i < 2; ++i) {
      int idx = tid + i * 256;
      int r = idx >> 3;
      int c4 = (idx & 7) * 4;
      float4 av = *(const float4*)(A + (size_t)(row0 + r) * HDIM + k0 + c4);
      As[c4 + 0][r] = av.x; As[c4 + 1][r] = av.y; As[c4 + 2][r] = av.z; As[c4 + 3][r] = av.w;
      float4 wv = *(const float4*)(W + (size_t)(col0 + r) * HDIM + k0 + c4);
      Ws[c4 + 0][r] = wv.x; Ws[c4 + 1][r] = wv.y; Ws[c4 + 2][r] = wv.z; Ws[c4 + 3][r] = wv.w;
    }
    __syncthreads();
#pragma unroll
    for (int kk = 0; kk < 32; ++kk) {
      float4 a4 = *(const float4*)&As[kk][ty * 4];
      float4 b4 = *(const float4*)&Ws[kk][tx * 4];
      float av[4] = {a4.x, a4.y, a4.z, a4.w};
      float bv[4] = {b4.x, b4.y, b4.z, b4.w};
#pragma unroll
      for (int i = 0; i < 4; ++i)
#pragma unroll
        for (int j = 0; j < 4; ++j)
          acc[i][j] += av[i] * bv[j];
    }
  }
#pragma unroll
  for (int i = 0; i < 4; ++i) {
    float4 o = make_float4(acc[i][0], acc[i][1], acc[i][2], acc[i][3]);
    *(float4*)(C + (size_t)(row0 + ty * 4 + i) * HDIM + col0 + tx * 4) = o;
  }
}

// ---------------------------------------------------------------------------
// Banded flash attention with MFMA. Block = (q-tile of 64 rows, bh).
// 256 threads = 4 waves; wave w owns rows sr=w*16 .. sr+15 of the tile.
__global__ __launch_bounds__(256) void attn_mfma(const float* __restrict__ q,
                                                 const float* __restrict__ k,
                                                 const float* __restrict__ v,
                                                 const bf16_t* __restrict__ pet,
                                                 float* __restrict__ ao) {
  __shared__ alignas(16) bf16_t Ks[64][72];    // key tile, [n][d], pad->144B rows
  __shared__ alignas(16) bf16_t Vts[64][72];   // value tile TRANSPOSED [d][n]
  __shared__ alignas(16) bf16_t Ps[64][72];    // softmax probs [i][n] (C->A relayout)
  __shared__ alignas(16) bf16_t Ts[64][132];   // pe-term ring buffer [i][l & 127]

  const int m0 = blockIdx.x * 64;
  const int bh = blockIdx.y;
  const int b = bh >> 3, kh = bh & 7;
  const int tid = threadIdx.x;
  const int lane = tid & 63, wave = tid >> 6;
  const int quad = lane >> 4, l16 = lane & 15;
  const int sr = wave * 16;

  // ---- Q fragments (A layout: row=lane&15, k=quad*8+j), scale 0.125 folded in
  bf16x8 qa[2];
  {
    const float* qrow = q + (size_t)(b * MQ + m0 + sr + l16) * HDIM + kh * 64;
#pragma unroll
    for (int ks = 0; ks < 2; ++ks) {
      const float* p4 = qrow + ks * 32 + quad * 8;
      float4 x = *(const float4*)p4;
      float4 y = *(const float4*)(p4 + 4);
      bf16x8 t;
      t[0] = (bf16_t)(x.x * 0.125f); t[1] = (bf16_t)(x.y * 0.125f);
      t[2] = (bf16_t)(x.z * 0.125f); t[3] = (bf16_t)(x.w * 0.125f);
      t[4] = (bf16_t)(y.x * 0.125f); t[5] = (bf16_t)(y.y * 0.125f);
      t[6] = (bf16_t)(y.z * 0.125f); t[7] = (bf16_t)(y.w * 0.125f);
      qa[ks] = t;
    }
  }

  f32x4 oacc[4] = {};           // O accumulator, 4 d-chunks, C layout
  float m_run[4], l_run[4];
#pragma unroll
  for (int r = 0; r < 4; ++r) { m_run[r] = -INFINITY; l_run[r] = 0.f; }

  const float* kbase = k + (size_t)(b * NK + m0) * HDIM + kh * 64;
  const float* vbase = v + (size_t)(b * NK + m0) * HDIM + kh * 64;

  for (int j = 0; j <= 16; ++j) {
    // ---- T ring update: add pe columns l in [64j, 64j+63] (j=0 seeds tile 0)
    if (j * 64 < LSPAN) {
      const int l0 = j * 64;
#pragma unroll
      for (int ch = 0; ch < 4; ++ch) {
        int l = l0 + ch * 16 + l16;
        bf16x8 pb0 = {}, pb1 = {};
        if (l < LSPAN) {  // l >= 0 always here
          pb0 = *(const bf16x8*)(pet + (size_t)l * 64 + quad * 8);
          pb1 = *(const bf16x8*)(pet + (size_t)l * 64 + 32 + quad * 8);
        }
        f32x4 t = {};
        t = MFMA16(qa[0], pb0, t);
        t = MFMA16(qa[1], pb1, t);
#pragma unroll
        for (int r = 0; r < 4; ++r)
          Ts[sr + quad * 4 + r][l & 127] = (bf16_t)t[r];
      }
    }
    // ---- stage K tile and V tile (transposed), fp32 -> bf16
    {
      const float* kg = kbase + (size_t)(j * 64) * HDIM;
      const float* vg = vbase + (size_t)(j * 64) * HDIM;
#pragma unroll
      for (int i = 0; i < 4; ++i) {
        int f = tid + i * 256;
        int r = f >> 4;
        int c4 = (f & 15) * 4;
        float4 kv = *(const float4*)(kg + (size_t)r * HDIM + c4);
        bf16x4 kb;
        kb[0] = (bf16_t)kv.x; kb[1] = (bf16_t)kv.y; kb[2] = (bf16_t)kv.z; kb[3] = (bf16_t)kv.w;
        *(bf16x4*)&Ks[r][c4] = kb;
        float4 vv = *(const float4*)(vg + (size_t)r * HDIM + c4);
        Vts[c4 + 0][r] = (bf16_t)vv.x;
        Vts[c4 + 1][r] = (bf16_t)vv.y;
        Vts[c4 + 2][r] = (bf16_t)vv.z;
        Vts[c4 + 3][r] = (bf16_t)vv.w;
      }
    }
    __syncthreads();

    // ---- S = Q·K^T (4 col-chunks of 16)
    f32x4 sacc[4];
#pragma unroll
    for (int ch = 0; ch < 4; ++ch) {
      bf16x8 kb0 = *(const bf16x8*)&Ks[ch * 16 + l16][quad * 8];
      bf16x8 kb1 = *(const bf16x8*)&Ks[ch * 16 + l16][32 + quad * 8];
      f32x4 s = {};
      s = MFMA16(qa[0], kb0, s);
      s = MFMA16(qa[1], kb1, s);
      sacc[ch] = s;
    }
    // ---- add pe term (skewed gather from Ts ring), mask band
    float p[4][4];
    float mt[4] = {-INFINITY, -INFINITY, -INFINITY, -INFINITY};
#pragma unroll
    for (int ch = 0; ch < 4; ++ch) {
#pragma unroll
      for (int r = 0; r < 4; ++r) {
        int il = quad * 4 + r;
        int l = j * 64 + ch * 16 + l16 - sr - il;
        float s;
        if (l >= 0 && l < LSPAN)
          s = sacc[ch][r] + (float)Ts[sr + il][l & 127];
        else
          s = -INFINITY;
        p[ch][r] = s;
        mt[r] = fmaxf(mt[r], s);
      }
    }
    // ---- online softmax (row stats live in the 16-lane col group)
#pragma unroll
    for (int r = 0; r < 4; ++r) {
      float m = mt[r];
      m = fmaxf(m, __shfl_xor(m, 1, 64));
      m = fmaxf(m, __shfl_xor(m, 2, 64));
      m = fmaxf(m, __shfl_xor(m, 4, 64));
      m = fmaxf(m, __shfl_xor(m, 8, 64));
      float mn = fmaxf(m_run[r], m);
      float alpha = __expf(m_run[r] - mn);  // first tile: exp(-inf)=0
      m_run[r] = mn;
      float rs = 0.f;
#pragma unroll
      for (int ch = 0; ch < 4; ++ch) {
        p[ch][r] = __expf(p[ch][r] - mn);
        rs += p[ch][r];
      }
      rs += __shfl_xor(rs, 1, 64);
      rs += __shfl_xor(rs, 2, 64);
      rs += __shfl_xor(rs, 4, 64);
      rs += __shfl_xor(rs, 8, 64);
      l_run[r] = l_run[r] * alpha + rs;
#pragma unroll
      for (int dch = 0; dch < 4; ++dch) oacc[dch][r] *= alpha;
    }
    // ---- P: C layout -> LDS (wave-private rows)
#pragma unroll
    for (int ch = 0; ch < 4; ++ch)
#pragma unroll
      for (int r = 0; r < 4; ++r)
        Ps[sr + quad * 4 + r][ch * 16 + l16] = (bf16_t)p[ch][r];
    __syncthreads();
    // ---- O += P·V
    bf16x8 pa0 = *(const bf16x8*)&Ps[sr + l16][quad * 8];
    bf16x8 pa1 = *(const bf16x8*)&Ps[sr + l16][32 + quad * 8];
#pragma unroll
    for (int dch = 0; dch < 4; ++dch) {
      bf16x8 vb0 = *(const bf16x8*)&Vts[dch * 16 + l16][quad * 8];
      bf16x8 vb1 = *(const bf16x8*)&Vts[dch * 16 + l16][32 + quad * 8];
      oacc[dch] = MFMA16(pa0, vb0, oacc[dch]);
      oacc[dch] = MFMA16(pa1, vb1, oacc[dch]);
    }
    __syncthreads();
  }

  // ---- epilogue: normalize and store
#pragma unroll
  for (int r = 0; r < 4; ++r) {
    float inv = 1.0f / l_run[r];
    int m = m0 + sr + quad * 4 + r;
#pragma unroll
    for (int dch = 0; dch < 4; ++dch)
      ao[(size_t)(b * MQ + m) * HDIM + kh * 64 + dch * 16 + l16] = oacc[dch][r] * inv;
  }
}

// ---------------------------------------------------------------------------
extern "C" void kernel_launch(void* const* d_in, const int* in_sizes, int n_in,
                              void* d_out, int out_size, void* d_ws, size_t ws_size,
                              hipStream_t stream) {
  const float* query  = (const float*)d_in[0];
  const float* key    = (const float*)d_in[1];
  const float* value  = (const float*)d_in[2];
  const float* key_pe = (const float*)d_in[3];
  const float* Wq     = (const float*)d_in[4];
  const float* Wk     = (const float*)d_in[5];
  const float* Wv     = (const float*)d_in[6];
  const float* Wo     = (const float*)d_in[7];
  float* out = (float*)d_out;

  float* ws  = (float*)d_ws;
  float* qws = ws;                     // [8,512,512]   = 2,097,152 f32
  float* kws = qws + 2097152;          // [8,1536,512]  = 6,291,456 f32
  float* vws = kws + 6291456;          // [8,1536,512]  = 6,291,456 f32
  float* aow = vws + 6291456;          // [8,512,512]   = 2,097,152 f32
  bf16_t* pet = (bf16_t*)(aow + 2097152);  // [1024,64] bf16 = 128 KB
  // total ~64.1 MB

  hipLaunchKernelGGL(transpose_pe, dim3(256), dim3(256), 0, stream, key_pe, pet);
  hipLaunchKernelGGL(gemm_nt, dim3(64, 8),  dim3(256), 0, stream, query, Wq, qws);
  hipLaunchKernelGGL(gemm_nt, dim3(192, 8), dim3(256), 0, stream, key,   Wk, kws);
  hipLaunchKernelGGL(gemm_nt, dim3(192, 8), dim3(256), 0, stream, value, Wv, vws);
  hipLaunchKernelGGL(attn_mfma, dim3(8, 64), dim3(256), 0, stream,
                     qws, kws, vws, pet, aow);
  hipLaunchKernelGGL(gemm_nt, dim3(64, 8), dim3(256), 0, stream, aow, Wo, out);
}

// Round 3
// 229.693 us; speedup vs baseline: 5.2632x; 1.8881x over previous
//
#include <hip/hip_runtime.h>
#include <hip/hip_bf16.h>
#include <cstddef>
#include <math.h>

// B=8, M=512, H=512, K=8 heads, D=64, L=1024, key len = 1536
// score[bh,m,l] = q[bh,m,:]·k[bh,m+l,:]*0.125 + q[bh,m,:]·pe_t[l,:]*0.125
// out[bh,m,:]  = sum_l softmax_l(score) * v[bh,m+l,:]

#define HDIM 512
#define MQ 512
#define NK 1536
#define LSPAN 1024

typedef _Float16 f16_t;
typedef f16_t f16x8 __attribute__((ext_vector_type(8)));
typedef f16_t f16x4 __attribute__((ext_vector_type(4)));
typedef float f32x4 __attribute__((ext_vector_type(4)));

#define MFMA16F(a, b, c) __builtin_amdgcn_mfma_f32_16x16x32_f16((a), (b), (c), 0, 0, 0)

__device__ __forceinline__ void async_cp16(const void* g, void* l) {
  __builtin_amdgcn_global_load_lds((const __attribute__((address_space(1))) void*)g,
                                   (__attribute__((address_space(3))) void*)l, 16, 0, 0);
}

// ---------------------------------------------------------------------------
// fp32 -> fp16 converts
__global__ void cvt_qkv(const float* __restrict__ q, const float* __restrict__ k,
                        const float* __restrict__ v, f16_t* __restrict__ q16,
                        f16_t* __restrict__ k16, f16_t* __restrict__ v16) {
  int y = blockIdx.y;
  const float* s = (y == 0) ? q : (y == 1) ? k : v;
  f16_t* d = (y == 0) ? q16 : (y == 1) ? k16 : v16;
  int n4 = (y == 0) ? (MQ * 8 * HDIM / 4) : (NK * 8 * HDIM / 4);
  int i = blockIdx.x * 256 + threadIdx.x;
  if (i >= n4) return;
  float4 x = ((const float4*)s)[i];
  f16x4 o;
  o[0] = (f16_t)x.x; o[1] = (f16_t)x.y; o[2] = (f16_t)x.z; o[3] = (f16_t)x.w;
  ((f16x4*)d)[i] = o;
}

__global__ void cvt_w4(const float* __restrict__ w0, const float* __restrict__ w1,
                       const float* __restrict__ w2, const float* __restrict__ w3,
                       f16_t* __restrict__ o0, f16_t* __restrict__ o1,
                       f16_t* __restrict__ o2, f16_t* __restrict__ o3) {
  int y = blockIdx.y;
  const float* s = (y == 0) ? w0 : (y == 1) ? w1 : (y == 2) ? w2 : w3;
  f16_t* d = (y == 0) ? o0 : (y == 1) ? o1 : (y == 2) ? o2 : o3;
  int i = blockIdx.x * 256 + threadIdx.x;  // 65536 float4s
  float4 x = ((const float4*)s)[i];
  f16x4 o;
  o[0] = (f16_t)x.x; o[1] = (f16_t)x.y; o[2] = (f16_t)x.z; o[3] = (f16_t)x.w;
  ((f16x4*)d)[i] = o;
}

// pe transpose + fp16 cast: [64,1024] f32 -> [1024,64] f16
__global__ void transpose_pe(const float* __restrict__ pe, f16_t* __restrict__ pet) {
  int idx = blockIdx.x * 256 + threadIdx.x;  // 65536
  int d = idx >> 10;
  int l = idx & 1023;
  pet[l * 64 + d] = (f16_t)pe[idx];
}

// ---------------------------------------------------------------------------
// Fused q/k/v projection GEMMs: C = A · W^T, fp16 in/out, MFMA 16x16x32_f16.
// 128x128 tile, BK=32, 256 threads (4 waves, each a 64x64 quadrant).
// Block map: [0,128) q-proj, [128,512) k-proj, [512,896) v-proj.
__global__ __launch_bounds__(256) void gemm3(
    const f16_t* __restrict__ qa, const f16_t* __restrict__ ka, const f16_t* __restrict__ va,
    const f16_t* __restrict__ wq, const f16_t* __restrict__ wk, const f16_t* __restrict__ wv,
    f16_t* __restrict__ qo, f16_t* __restrict__ ko, f16_t* __restrict__ vo) {
  __shared__ alignas(16) f16_t As[128][32];
  __shared__ alignas(16) f16_t Bs[128][32];

  int bx = blockIdx.x;
  const f16_t *A, *Bm;
  f16_t* C;
  int t;
  if (bx < 128)      { t = bx;       A = qa; Bm = wq; C = qo; }
  else if (bx < 512) { t = bx - 128; A = ka; Bm = wk; C = ko; }
  else               { t = bx - 512; A = va; Bm = wv; C = vo; }
  const int row0 = (t >> 2) * 128;
  const int col0 = (t & 3) * 128;

  const int tid = threadIdx.x;
  const int lane = tid & 63, wave = tid >> 6;
  const int quad = lane >> 4, l16 = lane & 15;
  const int rl = lane >> 2, cl = lane & 3;
  const int wr = (wave & 1) * 64, wc = (wave >> 1) * 64;

  f32x4 acc[4][4] = {};

  for (int k0 = 0; k0 < HDIM; k0 += 32) {
#pragma unroll
    for (int ii = 0; ii < 2; ++ii) {
      int g = wave * 2 + ii;
      async_cp16(A + (size_t)(row0 + g * 16 + rl) * HDIM + k0 + cl * 8, &As[g * 16][0]);
      async_cp16(Bm + (size_t)(col0 + g * 16 + rl) * HDIM + k0 + cl * 8, &Bs[g * 16][0]);
    }
    __syncthreads();
    f16x8 af[4], bf[4];
#pragma unroll
    for (int i = 0; i < 4; ++i) {
      af[i] = *(const f16x8*)&As[wr + i * 16 + l16][quad * 8];
      bf[i] = *(const f16x8*)&Bs[wc + i * 16 + l16][quad * 8];
    }
#pragma unroll
    for (int i = 0; i < 4; ++i)
#pragma unroll
      for (int n = 0; n < 4; ++n)
        acc[i][n] = MFMA16F(af[i], bf[n], acc[i][n]);
    __syncthreads();
  }
#pragma unroll
  for (int i = 0; i < 4; ++i)
#pragma unroll
    for (int n = 0; n < 4; ++n)
#pragma unroll
      for (int r = 0; r < 4; ++r)
        C[(size_t)(row0 + wr + i * 16 + quad * 4 + r) * HDIM + col0 + wc + n * 16 + l16] =
            (f16_t)acc[i][n][r];
}

// Wo GEMM: fp16 A (attn out), fp16 W, fp32 C (final output)
__global__ __launch_bounds__(256) void gemm_wo(const f16_t* __restrict__ A,
                                               const f16_t* __restrict__ Bm,
                                               float* __restrict__ C) {
  __shared__ alignas(16) f16_t As[128][32];
  __shared__ alignas(16) f16_t Bs[128][32];
  const int t = blockIdx.x;
  const int row0 = (t >> 2) * 128;
  const int col0 = (t & 3) * 128;
  const int tid = threadIdx.x;
  const int lane = tid & 63, wave = tid >> 6;
  const int quad = lane >> 4, l16 = lane & 15;
  const int rl = lane >> 2, cl = lane & 3;
  const int wr = (wave & 1) * 64, wc = (wave >> 1) * 64;

  f32x4 acc[4][4] = {};
  for (int k0 = 0; k0 < HDIM; k0 += 32) {
#pragma unroll
    for (int ii = 0; ii < 2; ++ii) {
      int g = wave * 2 + ii;
      async_cp16(A + (size_t)(row0 + g * 16 + rl) * HDIM + k0 + cl * 8, &As[g * 16][0]);
      async_cp16(Bm + (size_t)(col0 + g * 16 + rl) * HDIM + k0 + cl * 8, &Bs[g * 16][0]);
    }
    __syncthreads();
    f16x8 af[4], bf[4];
#pragma unroll
    for (int i = 0; i < 4; ++i) {
      af[i] = *(const f16x8*)&As[wr + i * 16 + l16][quad * 8];
      bf[i] = *(const f16x8*)&Bs[wc + i * 16 + l16][quad * 8];
    }
#pragma unroll
    for (int i = 0; i < 4; ++i)
#pragma unroll
      for (int n = 0; n < 4; ++n)
        acc[i][n] = MFMA16F(af[i], bf[n], acc[i][n]);
    __syncthreads();
  }
#pragma unroll
  for (int i = 0; i < 4; ++i)
#pragma unroll
    for (int n = 0; n < 4; ++n)
#pragma unroll
      for (int r = 0; r < 4; ++r)
        C[(size_t)(row0 + wr + i * 16 + quad * 4 + r) * HDIM + col0 + wc + n * 16 + l16] =
            acc[i][n][r];
}

// ---------------------------------------------------------------------------
// Banded flash attention, fp16 MFMA. Block = (64-row q-tile, bh); 4 waves.
__global__ __launch_bounds__(256) void attn_f16(const f16_t* __restrict__ q,
                                                const f16_t* __restrict__ k,
                                                const f16_t* __restrict__ v,
                                                const f16_t* __restrict__ pet,
                                                f16_t* __restrict__ ao) {
  __shared__ alignas(16) f16_t Ks[64][72];    // key tile [n][d], 144B rows (16B-mult)
  __shared__ alignas(16) f16_t Vts[64][72];   // value tile transposed [d][n]
  __shared__ alignas(16) f16_t Ps[64][72];    // probs [i][n]
  __shared__ alignas(16) f16_t Ts[64][132];   // pe-term ring [i][l & 127]

  const int m0 = blockIdx.x * 64;
  const int bh = blockIdx.y;
  const int b = bh >> 3, kh = bh & 7;
  const int tid = threadIdx.x;
  const int lane = tid & 63, wave = tid >> 6;
  const int quad = lane >> 4, l16 = lane & 15;
  const int sr = wave * 16;

  // Q fragments (A layout), 0.125 scale folded (exact in fp16)
  f16x8 qa[2];
  {
    const f16_t* qrow = q + (size_t)(b * MQ + m0 + sr + l16) * HDIM + kh * 64;
#pragma unroll
    for (int ks = 0; ks < 2; ++ks) {
      f16x8 tq = *(const f16x8*)(qrow + ks * 32 + quad * 8);
#pragma unroll
      for (int e = 0; e < 8; ++e) tq[e] = (f16_t)((float)tq[e] * 0.125f);
      qa[ks] = tq;
    }
  }

  f32x4 oacc[4] = {};
  float m_run[4], l_run[4];
#pragma unroll
  for (int r = 0; r < 4; ++r) { m_run[r] = -INFINITY; l_run[r] = 0.f; }

  const f16_t* kbase = k + (size_t)(b * NK + m0) * HDIM + kh * 64;
  const f16_t* vbase = v + (size_t)(b * NK + m0) * HDIM + kh * 64;

  for (int j = 0; j <= 16; ++j) {
    // T ring update: pe cols l in [64j, 64j+63]
    if (j * 64 < LSPAN) {
      const int l0 = j * 64;
#pragma unroll
      for (int ch = 0; ch < 4; ++ch) {
        int l = l0 + ch * 16 + l16;
        f16x8 pb0 = {}, pb1 = {};
        if (l < LSPAN) {
          pb0 = *(const f16x8*)(pet + (size_t)l * 64 + quad * 8);
          pb1 = *(const f16x8*)(pet + (size_t)l * 64 + 32 + quad * 8);
        }
        f32x4 tt = {};
        tt = MFMA16F(qa[0], pb0, tt);
        tt = MFMA16F(qa[1], pb1, tt);
#pragma unroll
        for (int r = 0; r < 4; ++r)
          Ts[sr + quad * 4 + r][l & 127] = (f16_t)tt[r];
      }
    }
    // stage K tile + transposed V tile (fp16 raw)
    {
      const f16_t* kg = kbase + (size_t)(j * 64) * HDIM;
      const f16_t* vg = vbase + (size_t)(j * 64) * HDIM;
#pragma unroll
      for (int i = 0; i < 2; ++i) {
        int f = tid + i * 256;
        int r = f >> 3;
        int c8 = (f & 7) * 8;
        f16x8 kv = *(const f16x8*)(kg + (size_t)r * HDIM + c8);
        *(f16x8*)&Ks[r][c8] = kv;
        f16x8 vv = *(const f16x8*)(vg + (size_t)r * HDIM + c8);
#pragma unroll
        for (int e = 0; e < 8; ++e) Vts[c8 + e][r] = vv[e];
      }
    }
    __syncthreads();

    // S = Q·K^T
    f32x4 sacc[4];
#pragma unroll
    for (int ch = 0; ch < 4; ++ch) {
      f16x8 kb0 = *(const f16x8*)&Ks[ch * 16 + l16][quad * 8];
      f16x8 kb1 = *(const f16x8*)&Ks[ch * 16 + l16][32 + quad * 8];
      f32x4 s = {};
      s = MFMA16F(qa[0], kb0, s);
      s = MFMA16F(qa[1], kb1, s);
      sacc[ch] = s;
    }
    // add pe term (skewed gather), band mask
    float p[4][4];
    float mt[4] = {-INFINITY, -INFINITY, -INFINITY, -INFINITY};
#pragma unroll
    for (int ch = 0; ch < 4; ++ch) {
#pragma unroll
      for (int r = 0; r < 4; ++r) {
        int il = quad * 4 + r;
        int l = j * 64 + ch * 16 + l16 - sr - il;
        float s;
        if (l >= 0 && l < LSPAN)
          s = sacc[ch][r] + (float)Ts[sr + il][l & 127];
        else
          s = -INFINITY;
        p[ch][r] = s;
        mt[r] = fmaxf(mt[r], s);
      }
    }
    // online softmax
#pragma unroll
    for (int r = 0; r < 4; ++r) {
      float m = mt[r];
      m = fmaxf(m, __shfl_xor(m, 1, 64));
      m = fmaxf(m, __shfl_xor(m, 2, 64));
      m = fmaxf(m, __shfl_xor(m, 4, 64));
      m = fmaxf(m, __shfl_xor(m, 8, 64));
      float mn = fmaxf(m_run[r], m);
      float alpha = __expf(m_run[r] - mn);
      m_run[r] = mn;
      float rs = 0.f;
#pragma unroll
      for (int ch = 0; ch < 4; ++ch) {
        p[ch][r] = __expf(p[ch][r] - mn);
        rs += p[ch][r];
      }
      rs += __shfl_xor(rs, 1, 64);
      rs += __shfl_xor(rs, 2, 64);
      rs += __shfl_xor(rs, 4, 64);
      rs += __shfl_xor(rs, 8, 64);
      l_run[r] = l_run[r] * alpha + rs;
#pragma unroll
      for (int dch = 0; dch < 4; ++dch) oacc[dch][r] *= alpha;
    }
    // P: C layout -> LDS (wave-private rows; same-wave read below, no barrier)
#pragma unroll
    for (int ch = 0; ch < 4; ++ch)
#pragma unroll
      for (int r = 0; r < 4; ++r)
        Ps[sr + quad * 4 + r][ch * 16 + l16] = (f16_t)p[ch][r];
    // O += P·V
    f16x8 pa0 = *(const f16x8*)&Ps[sr + l16][quad * 8];
    f16x8 pa1 = *(const f16x8*)&Ps[sr + l16][32 + quad * 8];
#pragma unroll
    for (int dch = 0; dch < 4; ++dch) {
      f16x8 vb0 = *(const f16x8*)&Vts[dch * 16 + l16][quad * 8];
      f16x8 vb1 = *(const f16x8*)&Vts[dch * 16 + l16][32 + quad * 8];
      oacc[dch] = MFMA16F(pa0, vb0, oacc[dch]);
      oacc[dch] = MFMA16F(pa1, vb1, oacc[dch]);
    }
    __syncthreads();
  }

  // epilogue
#pragma unroll
  for (int r = 0; r < 4; ++r) {
    float inv = 1.0f / l_run[r];
    int m = m0 + sr + quad * 4 + r;
#pragma unroll
    for (int dch = 0; dch < 4; ++dch)
      ao[(size_t)(b * MQ + m) * HDIM + kh * 64 + dch * 16 + l16] =
          (f16_t)(oacc[dch][r] * inv);
  }
}

// ---------------------------------------------------------------------------
extern "C" void kernel_launch(void* const* d_in, const int* in_sizes, int n_in,
                              void* d_out, int out_size, void* d_ws, size_t ws_size,
                              hipStream_t stream) {
  const float* query  = (const float*)d_in[0];
  const float* key    = (const float*)d_in[1];
  const float* value  = (const float*)d_in[2];
  const float* key_pe = (const float*)d_in[3];
  const float* Wq     = (const float*)d_in[4];
  const float* Wk     = (const float*)d_in[5];
  const float* Wv     = (const float*)d_in[6];
  const float* Wo     = (const float*)d_in[7];
  float* out = (float*)d_out;

  f16_t* ws = (f16_t*)d_ws;
  f16_t* query16 = ws;                      // 2,097,152 h   (reused as ao16 later)
  f16_t* key16   = query16 + 2097152;       // 6,291,456
  f16_t* value16 = key16 + 6291456;         // 6,291,456
  f16_t* q16     = value16 + 6291456;       // 2,097,152
  f16_t* k16     = q16 + 2097152;           // 6,291,456
  f16_t* v16     = k16 + 6291456;           // 6,291,456
  f16_t* pet     = v16 + 6291456;           // 65,536
  f16_t* wq16    = pet + 65536;             // 262,144
  f16_t* wk16    = wq16 + 262144;           // 262,144
  f16_t* wv16    = wk16 + 262144;           // 262,144
  f16_t* wo16    = wv16 + 262144;           // 262,144
  f16_t* ao16    = query16;                 // alias: query16 dead after gemm3
  // total = 30,474,240 halfs = 58.1 MB

  hipLaunchKernelGGL(cvt_qkv, dim3(6144, 3), dim3(256), 0, stream,
                     query, key, value, query16, key16, value16);
  hipLaunchKernelGGL(cvt_w4, dim3(256, 4), dim3(256), 0, stream,
                     Wq, Wk, Wv, Wo, wq16, wk16, wv16, wo16);
  hipLaunchKernelGGL(transpose_pe, dim3(256), dim3(256), 0, stream, key_pe, pet);
  hipLaunchKernelGGL(gemm3, dim3(896), dim3(256), 0, stream,
                     query16, key16, value16, wq16, wk16, wv16, q16, k16, v16);
  hipLaunchKernelGGL(attn_f16, dim3(8, 64), dim3(256), 0, stream,
                     q16, k16, v16, pet, ao16);
  hipLaunchKernelGGL(gemm_wo, dim3(128), dim3(256), 0, stream, ao16, wo16, out);
}